// Round 8
// baseline (1680.738 us; speedup 1.0000x reference)
//
#include <hip/hip_runtime.h>
#include <hip/hip_bf16.h>

// ---------------------------------------------------------------------------
// VQ-VAE forward, fp32. NCHW.
// R8: (a) VQ v3: codebook register-resident (2 rows/lane/wave), h transposed
// to point-major (reuses buffer A), per-point cross-lane/wave argmin merge
// with strict-< + index tie-break (bit-identical d values -> same winner as
// sequential scan; R3 lesson: d rounding must not change).
// (b) conv_gemm: cout-split across grid.y (4 blocks/CU on 64-cout layers).
// (c) 13 repack launches fused into 1.
// Per-output FMA order everywhere unchanged: (ci asc, kk asc), bias init.
// ---------------------------------------------------------------------------

__device__ __forceinline__ float rp_elem(const float* __restrict__ src,
                                         int i, int COUT, int CIN, int KK)
{
    const int co = i % COUT;
    const int t  = i / COUT;
    const int kk = t % KK;
    const int ci = t / KK;
    return src[(co * CIN + ci) * KK + kk];
}

// One kernel repacks all weights into WR (layout/offsets fixed).
__global__ __launch_bounds__(256) void repack_all(
    const float* __restrict__ e1,  const float* __restrict__ e2,
    const float* __restrict__ er1a, const float* __restrict__ er1b,
    const float* __restrict__ er2a, const float* __restrict__ er2b,
    const float* __restrict__ pre, const float* __restrict__ d1,
    const float* __restrict__ dr1a, const float* __restrict__ dr1b,
    const float* __restrict__ dr2a, const float* __restrict__ dr2b,
    const float* __restrict__ t1, float* __restrict__ WR)
{
    const int idx = blockIdx.x * 256 + threadIdx.x;
    if (idx >= 188928) return;
    float v;
    if      (idx < 512)    v = rp_elem(e1,   idx,          32,  1, 16);
    else if (idx < 33280)  v = rp_elem(e2,   idx - 512,    64, 32, 16);
    else if (idx < 51712)  v = rp_elem(er1a, idx - 33280,  32, 64,  9);
    else if (idx < 53760)  v = rp_elem(er1b, idx - 51712,  64, 32,  1);
    else if (idx < 72192)  v = rp_elem(er2a, idx - 53760,  32, 64,  9);
    else if (idx < 74240)  v = rp_elem(er2b, idx - 72192,  64, 32,  1);
    else if (idx < 78336)  v = rp_elem(pre,  idx - 74240,  64, 64,  1);
    else if (idx < 115200) v = rp_elem(d1,   idx - 78336,  64, 64,  9);
    else if (idx < 133632) v = rp_elem(dr1a, idx - 115200, 32, 64,  9);
    else if (idx < 135680) v = rp_elem(dr1b, idx - 133632, 64, 32,  1);
    else if (idx < 154112) v = rp_elem(dr2a, idx - 135680, 32, 64,  9);
    else if (idx < 156160) v = rp_elem(dr2b, idx - 154112, 64, 32,  1);
    else {
        const int i  = idx - 156160;          // t1: [par][ci*4+tap][co]
        const int co  = i & 31;
        const int tap = (i >> 5) & 3;
        const int ci  = (i >> 7) & 63;
        const int par = i >> 13;
        const int pr = par >> 1, pc = par & 1;
        const int ta = tap >> 1, tb = tap & 1;
        const int kh = (1 - pr) + 2 * ta, kw = (1 - pc) + 2 * tb;
        v = t1[((ci * 32 + co) * 4 + kh) * 4 + kw];
    }
    WR[idx] = v;
}

// GEMM-form conv. Block: CPB couts x 256 pixels (grid.y picks cout group);
// thread: CPTHD x 4 pixels. K-chunks double-buffered in LDS.
template<int CTOT, int CPB, int CIN, int K, int S, int PAD,
         bool RELU_IN, bool HAS_BIAS, bool RESID, bool RELU_OUT>
__global__ __launch_bounds__(256) void conv_gemm(
    const float* __restrict__ in, const float* __restrict__ wr,
    const float* __restrict__ bias, const float* __restrict__ resid,
    float* __restrict__ out,
    int H, int W, int OH, int OW)
{
    constexpr int KK  = K * K;
    constexpr int CIC = (K == 1) ? 8 : 1;
    constexpr int KC  = CIC * KK;
    constexpr int NCH = CIN / CIC;
    constexpr int NT  = 256;
    constexpr int CPTHD = CPB / 4;
    __shared__ __align__(16) float As[2][KC * NT];

    const int tid = threadIdx.x;
    const int tpx = tid & 63;
    const int tco = __builtin_amdgcn_readfirstlane(tid >> 6);
    const int co0 = blockIdx.y * CPB + tco * CPTHD;

    const int ohow = OH * OW;
    const int n_st = blockIdx.x * NT + tid;
    const int b_st = n_st / ohow;
    const int hw_s = n_st % ohow;
    const int ih0 = (hw_s / OW) * S - PAD;
    const int iw0 = (hw_s % OW) * S - PAD;
    const float* __restrict__ inb = in + (size_t)b_st * CIN * H * W;

    float acc[CPTHD][4];
#pragma unroll
    for (int c = 0; c < CPTHD; c++) {
        const float bz = HAS_BIAS ? bias[co0 + c] : 0.0f;
#pragma unroll
        for (int q = 0; q < 4; q++) acc[c][q] = bz;
    }

    float pf[KC];
    auto stage_load = [&](int ci0) {
#pragma unroll
        for (int cc = 0; cc < CIC; cc++) {
            const float* __restrict__ inc = inb + (size_t)(ci0 + cc) * H * W;
#pragma unroll
            for (int kk = 0; kk < KK; kk++) {
                const int kh = kk / K, kw = kk % K;
                const int ih = ih0 + kh, iw = iw0 + kw;
                float v = 0.0f;
                if (ih >= 0 && ih < H && iw >= 0 && iw < W)
                    v = inc[ih * W + iw];
                if (RELU_IN) v = fmaxf(v, 0.0f);
                pf[cc * KK + kk] = v;
            }
        }
    };

    stage_load(0);
#pragma unroll
    for (int t = 0; t < KC; t++) As[0][t * NT + tid] = pf[t];
    __syncthreads();

#pragma unroll 2
    for (int c = 0; c < NCH; c++) {
        const int cur = c & 1;
        if (c + 1 < NCH) stage_load((c + 1) * CIC);

#pragma unroll
        for (int t = 0; t < KC; t++) {
            const float4 a4 = *(const float4*)(As[cur] + t * NT + tpx * 4);
            const float* __restrict__ wk =
                wr + (size_t)(c * KC + t) * CTOT + co0;
#pragma unroll
            for (int cc = 0; cc < CPTHD; cc++) {
                const float w = wk[cc];
                acc[cc][0] = fmaf(a4.x, w, acc[cc][0]);
                acc[cc][1] = fmaf(a4.y, w, acc[cc][1]);
                acc[cc][2] = fmaf(a4.z, w, acc[cc][2]);
                acc[cc][3] = fmaf(a4.w, w, acc[cc][3]);
            }
        }

        if (c + 1 < NCH) {
#pragma unroll
            for (int t = 0; t < KC; t++) As[1 - cur][t * NT + tid] = pf[t];
        }
        __syncthreads();
    }

    const int n_c  = blockIdx.x * NT + tpx * 4;
    const int b_c  = n_c / ohow;
    const int hw_c = n_c % ohow;
    float* __restrict__ op = out + (size_t)b_c * CTOT * ohow + hw_c;
    const float* __restrict__ rp =
        RESID ? (resid + (size_t)b_c * CTOT * ohow + hw_c) : nullptr;
#pragma unroll
    for (int c = 0; c < CPTHD; c++) {
        const size_t off = (size_t)(co0 + c) * ohow;
        float4 r = make_float4(acc[c][0], acc[c][1], acc[c][2], acc[c][3]);
        if (RESID) {
            const float4 rv = *(const float4*)(rp + off);
            r.x += rv.x; r.y += rv.y; r.z += rv.z; r.w += rv.w;
        }
        if (RELU_OUT) {
            r.x = fmaxf(r.x, 0.f); r.y = fmaxf(r.y, 0.f);
            r.z = fmaxf(r.z, 0.f); r.w = fmaxf(r.w, 0.f);
        }
        *(float4*)(op + off) = r;
    }
}

// GEMM-form transposed conv t1 (64 -> 32, 4x4 s2 p1), per parity class.
__global__ __launch_bounds__(256) void convt_gemm(
    const float* __restrict__ in, const float* __restrict__ wr,  // [par][256][32]
    const float* __restrict__ bias, float* __restrict__ out,
    int IH, int IW)
{
    constexpr int NT = 256, KC = 8, KTOT = 256, CTOT = 32, CPTHD = 8;
    __shared__ __align__(16) float As[KC * NT];

    const int tid = threadIdx.x;
    const int tpx = tid & 63;
    const int tco = __builtin_amdgcn_readfirstlane(tid >> 6);
    const int co0 = tco * CPTHD;
    const int par = blockIdx.y;
    const int pr = par >> 1, pc = par & 1;
    const int ihiw = IH * IW;
    const int OH = IH * 2, OW = IW * 2;

    const int n_st = blockIdx.x * NT + tid;
    const int b_st = n_st / ihiw;
    const int r_s  = n_st % ihiw;
    const int i_st = r_s / IW;
    const int j_st = r_s % IW;
    const float* __restrict__ inb = in + (size_t)b_st * 64 * ihiw;

    float acc[CPTHD][4];
#pragma unroll
    for (int c = 0; c < CPTHD; c++) {
        const float bz = bias[co0 + c];
#pragma unroll
        for (int q = 0; q < 4; q++) acc[c][q] = bz;
    }

    const float* __restrict__ wpar = wr + (size_t)par * KTOT * CTOT;

#pragma unroll 1
    for (int k0 = 0; k0 < KTOT; k0 += KC) {
        __syncthreads();
#pragma unroll
        for (int t = 0; t < KC; t++) {
            const int k  = k0 + t;
            const int ci = k >> 2;
            const int ta = (k >> 1) & 1;
            const int tb = k & 1;
            const int ih = i_st + pr - ta;
            const int iw = j_st + pc - tb;
            float v = 0.0f;
            if (ih >= 0 && ih < IH && iw >= 0 && iw < IW)
                v = inb[(size_t)ci * ihiw + ih * IW + iw];
            As[t * NT + tid] = v;
        }
        __syncthreads();
#pragma unroll
        for (int t = 0; t < KC; t++) {
            const float4 a4 = *(const float4*)(As + t * NT + tpx * 4);
            const float* __restrict__ wk = wpar + (size_t)(k0 + t) * CTOT + co0;
#pragma unroll
            for (int c = 0; c < CPTHD; c++) {
                const float w = wk[c];
                acc[c][0] = fmaf(a4.x, w, acc[c][0]);
                acc[c][1] = fmaf(a4.y, w, acc[c][1]);
                acc[c][2] = fmaf(a4.z, w, acc[c][2]);
                acc[c][3] = fmaf(a4.w, w, acc[c][3]);
            }
        }
    }

    const int n_c = blockIdx.x * NT + tpx * 4;
    const int b_c = n_c / ihiw;
    const int r_c = n_c % ihiw;
    const int i_c = r_c / IW;
    const int j_c = r_c % IW;
    const int oh = 2 * i_c + pr;
    float* __restrict__ ob = out + (size_t)b_c * CTOT * OH * OW + (size_t)oh * OW;
#pragma unroll
    for (int c = 0; c < CPTHD; c++) {
        const size_t off = (size_t)(co0 + c) * OH * OW;
#pragma unroll
        for (int q = 0; q < 4; q++)
            ob[off + 2 * (j_c + q) + pc] = fmaxf(acc[c][q], 0.0f);
    }
}

// Final transposed conv (32 -> 1). (validated)
__global__ __launch_bounds__(256) void convt2_quad(
    const float* __restrict__ in, const float* __restrict__ w,
    const float* __restrict__ bias, float* __restrict__ out, int B)
{
    const int IH = 128, IW = 128, CIN = 32, OW = 256;
    const int j = threadIdx.x & 127;
    const int i = (blockIdx.x << 1) + (threadIdx.x >> 7);
    const int b = blockIdx.y;

    const float* __restrict__ inb = in + (size_t)b * CIN * IH * IW;
    const float bz = bias[0];
    float a00 = bz, a01 = bz, a10 = bz, a11 = bz;

    const bool okm = (i > 0);
    const bool okp = (i < IH - 1);
    const bool olm = (j > 0);
    const bool olp = (j < IW - 1);

#pragma unroll 4
    for (int ci = 0; ci < CIN; ci++) {
        const float* __restrict__ p = inb + ((size_t)ci * IH + i) * IW + j;
        const float* __restrict__ wp = w + ci * 16;
        const float vmm = (okm && olm) ? p[-IW - 1] : 0.f;
        const float vm0 = okm ? p[-IW] : 0.f;
        const float vmp = (okm && olp) ? p[-IW + 1] : 0.f;
        const float v0m = olm ? p[-1] : 0.f;
        const float v00 = p[0];
        const float v0p = olp ? p[1] : 0.f;
        const float vpm = (okp && olm) ? p[IW - 1] : 0.f;
        const float vp0 = okp ? p[IW] : 0.f;
        const float vpp = (okp && olp) ? p[IW + 1] : 0.f;
        a00 = fmaf(v00, wp[1 * 4 + 1], a00);
        a00 = fmaf(v0m, wp[1 * 4 + 3], a00);
        a00 = fmaf(vm0, wp[3 * 4 + 1], a00);
        a00 = fmaf(vmm, wp[3 * 4 + 3], a00);
        a01 = fmaf(v0p, wp[1 * 4 + 0], a01);
        a01 = fmaf(v00, wp[1 * 4 + 2], a01);
        a01 = fmaf(vmp, wp[3 * 4 + 0], a01);
        a01 = fmaf(vm0, wp[3 * 4 + 2], a01);
        a10 = fmaf(vp0, wp[0 * 4 + 1], a10);
        a10 = fmaf(vpm, wp[0 * 4 + 3], a10);
        a10 = fmaf(v00, wp[2 * 4 + 1], a10);
        a10 = fmaf(v0m, wp[2 * 4 + 3], a10);
        a11 = fmaf(vpp, wp[0 * 4 + 0], a11);
        a11 = fmaf(vp0, wp[0 * 4 + 2], a11);
        a11 = fmaf(v0p, wp[2 * 4 + 0], a11);
        a11 = fmaf(v00, wp[2 * 4 + 2], a11);
    }

    float* __restrict__ outb = out + (size_t)b * 256 * 256;
    ((float2*)(outb + (size_t)(2 * i) * OW))[j] = make_float2(a00, a01);
    ((float2*)(outb + (size_t)(2 * i + 1) * OW))[j] = make_float2(a10, a11);
}

// h (B,64,HW) -> hT (B*HW, 64), exact copy (values untouched).
__global__ __launch_bounds__(256) void transpose_h(
    const float* __restrict__ h, float* __restrict__ hT)
{
    __shared__ float t[64][65];
    const int tid = threadIdx.x;
    const int hw0 = blockIdx.x * 64;
    const int b = blockIdx.y;
    const int l = tid & 63, r0 = tid >> 6;
#pragma unroll
    for (int r = r0; r < 64; r += 4)
        t[r][l] = h[((size_t)b * 64 + r) * 4096 + hw0 + l];
    __syncthreads();
#pragma unroll
    for (int r = r0; r < 64; r += 4)
        hT[((size_t)b * 4096 + hw0 + r) * 64 + l] = t[l][r];
}

// VQ v3. Block = 256 consecutive points. Wave w holds codes [w*128,(w+1)*128)
// register-resident (2 rows/lane). d = xx - 2.f*dot + ee with the exact R7
// chains (i ascending fmaf); argmin via strict-< with index tie-break ==
// sequential-scan winner. DO NOT alter any chain order (R3).
__global__ __launch_bounds__(256) void vq3_kernel(
    const float* __restrict__ hT,  // (131072, 64)
    const float* __restrict__ cb,  // (512,64)
    float* __restrict__ q)         // (B,64,4096)
{
    __shared__ float xx_sh[256];
    __shared__ float pd[4 * 256];
    __shared__ int   pk[4 * 256];
    __shared__ int   bidx_sh[256];

    const int tid = threadIdx.x;
    const int l = tid & 63;
    const int w = tid >> 6;
    const int n0 = blockIdx.x * 256;

    // codebook rows for this lane (one-time, register-resident)
    const int k0 = w * 128 + l;
    const int k1 = k0 + 64;
    float c0[64], c1[64];
#pragma unroll
    for (int i = 0; i < 16; i++) {
        const float4 a = *(const float4*)(cb + (size_t)k0 * 64 + 4 * i);
        c0[4 * i] = a.x; c0[4 * i + 1] = a.y; c0[4 * i + 2] = a.z; c0[4 * i + 3] = a.w;
        const float4 b = *(const float4*)(cb + (size_t)k1 * 64 + 4 * i);
        c1[4 * i] = b.x; c1[4 * i + 1] = b.y; c1[4 * i + 2] = b.z; c1[4 * i + 3] = b.w;
    }
    float e0 = 0.0f, e1 = 0.0f;
#pragma unroll
    for (int i = 0; i < 64; i++) e0 = fmaf(c0[i], c0[i], e0);
#pragma unroll
    for (int i = 0; i < 64; i++) e1 = fmaf(c1[i], c1[i], e1);

    // phase 0: xx per point (same asc fmaf chain as before)
    {
        const float* __restrict__ xs = hT + (size_t)(n0 + tid) * 64;
        float s = 0.0f;
#pragma unroll
        for (int i = 0; i < 64; i++) { const float v = xs[i]; s = fmaf(v, v, s); }
        xx_sh[tid] = s;
    }
    __syncthreads();

    // phase 1: each wave scans its 128 codes for all 256 points
#pragma unroll 1
    for (int pt = 0; pt < 256; pt++) {
        const int off = __builtin_amdgcn_readfirstlane((n0 + pt) << 6);
        const float* __restrict__ xs = hT + off;
        float d0 = 0.0f, d1 = 0.0f;
#pragma unroll
        for (int i = 0; i < 64; i++) {
            const float xv = xs[i];
            d0 = fmaf(xv, c0[i], d0);
            d1 = fmaf(xv, c1[i], d1);
        }
        const float xx = xx_sh[pt];
        const float da = xx - 2.0f * d0 + e0;
        const float db = xx - 2.0f * d1 + e1;
        float bd = da; int bk = k0;
        if (db < bd) { bd = db; bk = k1; }
#pragma unroll
        for (int m = 1; m < 64; m <<= 1) {
            const float od = __shfl_xor(bd, m, 64);
            const int   ok = __shfl_xor(bk, m, 64);
            if (od < bd || (od == bd && ok < bk)) { bd = od; bk = ok; }
        }
        if (l == 0) { pd[w * 256 + pt] = bd; pk[w * 256 + pt] = bk; }
    }
    __syncthreads();

    // phase 2: merge 4 wave-partials per point (ascending w; strict < —
    // equal d across waves implies larger k at larger w, so lower w wins)
    {
        float bd = pd[tid]; int bk = pk[tid];
#pragma unroll
        for (int ww = 1; ww < 4; ww++) {
            const float od = pd[ww * 256 + tid];
            if (od < bd) { bd = od; bk = pk[ww * 256 + tid]; }
        }
        bidx_sh[tid] = bk;
    }
    __syncthreads();

    // phase 3: gather + coalesced store (values from cb rows, exact)
    {
        const int b = n0 >> 12;
        const int hw = (n0 & 4095) + tid;
        const float4* __restrict__ cp4 =
            (const float4*)(cb + (size_t)bidx_sh[tid] * 64);
        float vals[64];
#pragma unroll
        for (int i = 0; i < 16; i++) {
            const float4 v = cp4[i];
            vals[4 * i] = v.x; vals[4 * i + 1] = v.y;
            vals[4 * i + 2] = v.z; vals[4 * i + 3] = v.w;
        }
        float* __restrict__ qb = q + (size_t)b * 64 * 4096 + hw;
#pragma unroll
        for (int i = 0; i < 64; i++) qb[(size_t)i * 4096] = vals[i];
    }
}

extern "C" void kernel_launch(void* const* d_in, const int* in_sizes, int n_in,
                              void* d_out, int out_size, void* d_ws, size_t ws_size,
                              hipStream_t stream) {
    const float* x      = (const float*)d_in[0];
    const float* w_e1   = (const float*)d_in[1];
    const float* b_e1   = (const float*)d_in[2];
    const float* w_e2   = (const float*)d_in[3];
    const float* b_e2   = (const float*)d_in[4];
    const float* w_er1a = (const float*)d_in[5];
    const float* w_er1b = (const float*)d_in[6];
    const float* w_er2a = (const float*)d_in[7];
    const float* w_er2b = (const float*)d_in[8];
    const float* w_pre  = (const float*)d_in[9];
    const float* b_pre  = (const float*)d_in[10];
    const float* cbk    = (const float*)d_in[11];
    const float* w_d1   = (const float*)d_in[12];
    const float* b_d1   = (const float*)d_in[13];
    const float* w_dr1a = (const float*)d_in[14];
    const float* w_dr1b = (const float*)d_in[15];
    const float* w_dr2a = (const float*)d_in[16];
    const float* w_dr2b = (const float*)d_in[17];
    const float* w_t1   = (const float*)d_in[18];
    const float* b_t1   = (const float*)d_in[19];
    const float* w_t2   = (const float*)d_in[20];
    const float* b_t2   = (const float*)d_in[21];
    float* out = (float*)d_out;

    float* A  = (float*)d_ws;            // (32,32,128,128) = 16777216 (also hT at VQ time)
    float* Bb = A  + 16777216;           // (32,64,64,64)   = 8388608
    float* C  = Bb + 8388608;            // (32,32,64,64)   = 4194304
    float* D  = C  + 4194304;            // (32,64,64,64)   = 8388608
    float* WR = D  + 8388608;            // repacked weights (188928)

    float* r_e1  = WR;
    float* r_e2  = WR + 512;
    float* r_er1a = WR + 33280;
    float* r_er1b = WR + 51712;
    float* r_er2a = WR + 53760;
    float* r_er2b = WR + 72192;
    float* r_pre = WR + 74240;
    float* r_d1  = WR + 78336;
    float* r_dr1a = WR + 115200;
    float* r_dr1b = WR + 133632;
    float* r_dr2a = WR + 135680;
    float* r_dr2b = WR + 154112;
    float* r_t1  = WR + 156160;

    const dim3 blk(256);

    repack_all<<<dim3(738), blk, 0, stream>>>(
        w_e1, w_e2, w_er1a, w_er1b, w_er2a, w_er2b, w_pre, w_d1,
        w_dr1a, w_dr1b, w_dr2a, w_dr2b, w_t1, WR);

    // Encoder
    conv_gemm<32, 32, 1, 4, 2, 1, false, true, false, true>
        <<<dim3(2048, 1), blk, 0, stream>>>(x, r_e1, b_e1, nullptr, A,
                                            256, 256, 128, 128);
    conv_gemm<64, 32, 32, 4, 2, 1, false, true, false, false>
        <<<dim3(512, 2), blk, 0, stream>>>(A, r_e2, b_e2, nullptr, Bb,
                                           128, 128, 64, 64);
    conv_gemm<32, 32, 64, 3, 1, 1, true, false, false, false>
        <<<dim3(512, 1), blk, 0, stream>>>(Bb, r_er1a, nullptr, nullptr, C,
                                           64, 64, 64, 64);
    conv_gemm<64, 32, 32, 1, 1, 0, true, false, true, false>
        <<<dim3(512, 2), blk, 0, stream>>>(C, r_er1b, nullptr, Bb, Bb,
                                           64, 64, 64, 64);
    conv_gemm<32, 32, 64, 3, 1, 1, true, false, false, false>
        <<<dim3(512, 1), blk, 0, stream>>>(Bb, r_er2a, nullptr, nullptr, C,
                                           64, 64, 64, 64);
    conv_gemm<64, 32, 32, 1, 1, 0, true, false, true, false>
        <<<dim3(512, 2), blk, 0, stream>>>(C, r_er2b, nullptr, Bb, Bb,
                                           64, 64, 64, 64);
    conv_gemm<64, 32, 64, 1, 1, 0, false, true, false, false>
        <<<dim3(512, 2), blk, 0, stream>>>(Bb, r_pre, b_pre, nullptr, D,
                                           64, 64, 64, 64);
    // VQ: transpose D into A (point-major), then vq3 D-free scan -> Bb
    transpose_h<<<dim3(64, 32), blk, 0, stream>>>(D, A);
    vq3_kernel<<<dim3(512), blk, 0, stream>>>(A, cbk, Bb);
    // Decoder
    conv_gemm<64, 32, 64, 3, 1, 1, false, true, false, false>
        <<<dim3(512, 2), blk, 0, stream>>>(Bb, r_d1, b_d1, nullptr, D,
                                           64, 64, 64, 64);
    conv_gemm<32, 32, 64, 3, 1, 1, true, false, false, false>
        <<<dim3(512, 1), blk, 0, stream>>>(D, r_dr1a, nullptr, nullptr, C,
                                           64, 64, 64, 64);
    conv_gemm<64, 32, 32, 1, 1, 0, true, false, true, false>
        <<<dim3(512, 2), blk, 0, stream>>>(C, r_dr1b, nullptr, D, D,
                                           64, 64, 64, 64);
    conv_gemm<32, 32, 64, 3, 1, 1, true, false, false, false>
        <<<dim3(512, 1), blk, 0, stream>>>(D, r_dr2a, nullptr, nullptr, C,
                                           64, 64, 64, 64);
    conv_gemm<64, 32, 32, 1, 1, 0, true, false, true, false>
        <<<dim3(512, 2), blk, 0, stream>>>(C, r_dr2b, nullptr, D, D,
                                           64, 64, 64, 64);
    // t1
    convt_gemm<<<dim3(512, 4), blk, 0, stream>>>(D, r_t1, b_t1, A, 64, 64);
    // t2
    convt2_quad<<<dim3(64, 32), blk, 0, stream>>>(A, w_t2, b_t2, out, 32);
}

// Round 9
// 1423.574 us; speedup vs baseline: 1.1806x; 1.1806x over previous
//
#include <hip/hip_runtime.h>
#include <hip/hip_bf16.h>

// ---------------------------------------------------------------------------
// VQ-VAE forward, fp32. NCHW.
// R9: VQ as a GEMM (conv_gemm structure): block=128 points in LDS, 4 waves
// split 512 codes, lane owns 2 points x 8-code chunks; codebook dim-major
// (cbT) via wave-uniform s_load. Per-(point,code) dot chain = ascending-i
// fmaf (bit-identical to R7); per-point scan ascending codes, strict <,
// ascending-w merge -> argmin identical to sequential scan (R3 lesson).
// Convs: R8's validated conv_gemm/convt_gemm/convt2_quad unchanged.
// R8 failure note: register-resident-codebook VQ spilled (VGPR=88) — the
// GEMM form keeps codebook in SGPRs per k-step instead.
// ---------------------------------------------------------------------------

__device__ __forceinline__ float rp_elem(const float* __restrict__ src,
                                         int i, int COUT, int CIN, int KK)
{
    const int co = i % COUT;
    const int t  = i / COUT;
    const int kk = t % KK;
    const int ci = t / KK;
    return src[(co * CIN + ci) * KK + kk];
}

// One kernel repacks all weights + codebook-transpose into WR.
__global__ __launch_bounds__(256) void repack_all(
    const float* __restrict__ e1,  const float* __restrict__ e2,
    const float* __restrict__ er1a, const float* __restrict__ er1b,
    const float* __restrict__ er2a, const float* __restrict__ er2b,
    const float* __restrict__ pre, const float* __restrict__ d1,
    const float* __restrict__ dr1a, const float* __restrict__ dr1b,
    const float* __restrict__ dr2a, const float* __restrict__ dr2b,
    const float* __restrict__ t1, const float* __restrict__ cb,
    float* __restrict__ WR)
{
    const int idx = blockIdx.x * 256 + threadIdx.x;
    if (idx >= 221696) return;
    float v;
    if      (idx < 512)    v = rp_elem(e1,   idx,          32,  1, 16);
    else if (idx < 33280)  v = rp_elem(e2,   idx - 512,    64, 32, 16);
    else if (idx < 51712)  v = rp_elem(er1a, idx - 33280,  32, 64,  9);
    else if (idx < 53760)  v = rp_elem(er1b, idx - 51712,  64, 32,  1);
    else if (idx < 72192)  v = rp_elem(er2a, idx - 53760,  32, 64,  9);
    else if (idx < 74240)  v = rp_elem(er2b, idx - 72192,  64, 32,  1);
    else if (idx < 78336)  v = rp_elem(pre,  idx - 74240,  64, 64,  1);
    else if (idx < 115200) v = rp_elem(d1,   idx - 78336,  64, 64,  9);
    else if (idx < 133632) v = rp_elem(dr1a, idx - 115200, 32, 64,  9);
    else if (idx < 135680) v = rp_elem(dr1b, idx - 133632, 64, 32,  1);
    else if (idx < 154112) v = rp_elem(dr2a, idx - 135680, 32, 64,  9);
    else if (idx < 156160) v = rp_elem(dr2b, idx - 154112, 64, 32,  1);
    else if (idx < 188928) {
        const int i  = idx - 156160;          // t1: [par][ci*4+tap][co]
        const int co  = i & 31;
        const int tap = (i >> 5) & 3;
        const int ci  = (i >> 7) & 63;
        const int par = i >> 13;
        const int pr = par >> 1, pc = par & 1;
        const int ta = tap >> 1, tb = tap & 1;
        const int kh = (1 - pr) + 2 * ta, kw = (1 - pc) + 2 * tb;
        v = t1[((ci * 32 + co) * 4 + kh) * 4 + kw];
    } else {
        const int i = idx - 188928;           // cbT: [dim][code]
        const int code = i & 511;
        const int dim  = i >> 9;
        v = cb[code * 64 + dim];
    }
    WR[idx] = v;
}

// ee[k] = sum_i cb[k][i]^2, exact ascending fmaf chain (matches reference).
__global__ __launch_bounds__(256) void vq_prep_ee(
    const float* __restrict__ cb, float* __restrict__ ee)
{
    const int k = blockIdx.x * 256 + threadIdx.x;  // grid(2) -> k < 512
    const float* __restrict__ cp = cb + (size_t)k * 64;
    float s = 0.0f;
#pragma unroll
    for (int i = 0; i < 64; i++) s = fmaf(cp[i], cp[i], s);
    ee[k] = s;
}

// GEMM-form conv (validated R8). Block: CPB couts x 256 pixels; thread:
// CPTHD x 4 pixels. K-chunks double-buffered in LDS.
template<int CTOT, int CPB, int CIN, int K, int S, int PAD,
         bool RELU_IN, bool HAS_BIAS, bool RESID, bool RELU_OUT>
__global__ __launch_bounds__(256) void conv_gemm(
    const float* __restrict__ in, const float* __restrict__ wr,
    const float* __restrict__ bias, const float* __restrict__ resid,
    float* __restrict__ out,
    int H, int W, int OH, int OW)
{
    constexpr int KK  = K * K;
    constexpr int CIC = (K == 1) ? 8 : 1;
    constexpr int KC  = CIC * KK;
    constexpr int NCH = CIN / CIC;
    constexpr int NT  = 256;
    constexpr int CPTHD = CPB / 4;
    __shared__ __align__(16) float As[2][KC * NT];

    const int tid = threadIdx.x;
    const int tpx = tid & 63;
    const int tco = __builtin_amdgcn_readfirstlane(tid >> 6);
    const int co0 = blockIdx.y * CPB + tco * CPTHD;

    const int ohow = OH * OW;
    const int n_st = blockIdx.x * NT + tid;
    const int b_st = n_st / ohow;
    const int hw_s = n_st % ohow;
    const int ih0 = (hw_s / OW) * S - PAD;
    const int iw0 = (hw_s % OW) * S - PAD;
    const float* __restrict__ inb = in + (size_t)b_st * CIN * H * W;

    float acc[CPTHD][4];
#pragma unroll
    for (int c = 0; c < CPTHD; c++) {
        const float bz = HAS_BIAS ? bias[co0 + c] : 0.0f;
#pragma unroll
        for (int q = 0; q < 4; q++) acc[c][q] = bz;
    }

    float pf[KC];
    auto stage_load = [&](int ci0) {
#pragma unroll
        for (int cc = 0; cc < CIC; cc++) {
            const float* __restrict__ inc = inb + (size_t)(ci0 + cc) * H * W;
#pragma unroll
            for (int kk = 0; kk < KK; kk++) {
                const int kh = kk / K, kw = kk % K;
                const int ih = ih0 + kh, iw = iw0 + kw;
                float v = 0.0f;
                if (ih >= 0 && ih < H && iw >= 0 && iw < W)
                    v = inc[ih * W + iw];
                if (RELU_IN) v = fmaxf(v, 0.0f);
                pf[cc * KK + kk] = v;
            }
        }
    };

    stage_load(0);
#pragma unroll
    for (int t = 0; t < KC; t++) As[0][t * NT + tid] = pf[t];
    __syncthreads();

#pragma unroll 2
    for (int c = 0; c < NCH; c++) {
        const int cur = c & 1;
        if (c + 1 < NCH) stage_load((c + 1) * CIC);

#pragma unroll
        for (int t = 0; t < KC; t++) {
            const float4 a4 = *(const float4*)(As[cur] + t * NT + tpx * 4);
            const float* __restrict__ wk =
                wr + (size_t)(c * KC + t) * CTOT + co0;
#pragma unroll
            for (int cc = 0; cc < CPTHD; cc++) {
                const float w = wk[cc];
                acc[cc][0] = fmaf(a4.x, w, acc[cc][0]);
                acc[cc][1] = fmaf(a4.y, w, acc[cc][1]);
                acc[cc][2] = fmaf(a4.z, w, acc[cc][2]);
                acc[cc][3] = fmaf(a4.w, w, acc[cc][3]);
            }
        }

        if (c + 1 < NCH) {
#pragma unroll
            for (int t = 0; t < KC; t++) As[1 - cur][t * NT + tid] = pf[t];
        }
        __syncthreads();
    }

    const int n_c  = blockIdx.x * NT + tpx * 4;
    const int b_c  = n_c / ohow;
    const int hw_c = n_c % ohow;
    float* __restrict__ op = out + (size_t)b_c * CTOT * ohow + hw_c;
    const float* __restrict__ rp =
        RESID ? (resid + (size_t)b_c * CTOT * ohow + hw_c) : nullptr;
#pragma unroll
    for (int c = 0; c < CPTHD; c++) {
        const size_t off = (size_t)(co0 + c) * ohow;
        float4 r = make_float4(acc[c][0], acc[c][1], acc[c][2], acc[c][3]);
        if (RESID) {
            const float4 rv = *(const float4*)(rp + off);
            r.x += rv.x; r.y += rv.y; r.z += rv.z; r.w += rv.w;
        }
        if (RELU_OUT) {
            r.x = fmaxf(r.x, 0.f); r.y = fmaxf(r.y, 0.f);
            r.z = fmaxf(r.z, 0.f); r.w = fmaxf(r.w, 0.f);
        }
        *(float4*)(op + off) = r;
    }
}

// GEMM-form transposed conv t1 (validated R8).
__global__ __launch_bounds__(256) void convt_gemm(
    const float* __restrict__ in, const float* __restrict__ wr,  // [par][256][32]
    const float* __restrict__ bias, float* __restrict__ out,
    int IH, int IW)
{
    constexpr int NT = 256, KC = 8, KTOT = 256, CTOT = 32, CPTHD = 8;
    __shared__ __align__(16) float As[KC * NT];

    const int tid = threadIdx.x;
    const int tpx = tid & 63;
    const int tco = __builtin_amdgcn_readfirstlane(tid >> 6);
    const int co0 = tco * CPTHD;
    const int par = blockIdx.y;
    const int pr = par >> 1, pc = par & 1;
    const int ihiw = IH * IW;
    const int OH = IH * 2, OW = IW * 2;

    const int n_st = blockIdx.x * NT + tid;
    const int b_st = n_st / ihiw;
    const int r_s  = n_st % ihiw;
    const int i_st = r_s / IW;
    const int j_st = r_s % IW;
    const float* __restrict__ inb = in + (size_t)b_st * 64 * ihiw;

    float acc[CPTHD][4];
#pragma unroll
    for (int c = 0; c < CPTHD; c++) {
        const float bz = bias[co0 + c];
#pragma unroll
        for (int q = 0; q < 4; q++) acc[c][q] = bz;
    }

    const float* __restrict__ wpar = wr + (size_t)par * KTOT * CTOT;

#pragma unroll 1
    for (int k0 = 0; k0 < KTOT; k0 += KC) {
        __syncthreads();
#pragma unroll
        for (int t = 0; t < KC; t++) {
            const int k  = k0 + t;
            const int ci = k >> 2;
            const int ta = (k >> 1) & 1;
            const int tb = k & 1;
            const int ih = i_st + pr - ta;
            const int iw = j_st + pc - tb;
            float v = 0.0f;
            if (ih >= 0 && ih < IH && iw >= 0 && iw < IW)
                v = inb[(size_t)ci * ihiw + ih * IW + iw];
            As[t * NT + tid] = v;
        }
        __syncthreads();
#pragma unroll
        for (int t = 0; t < KC; t++) {
            const float4 a4 = *(const float4*)(As + t * NT + tpx * 4);
            const float* __restrict__ wk = wpar + (size_t)(k0 + t) * CTOT + co0;
#pragma unroll
            for (int c = 0; c < CPTHD; c++) {
                const float w = wk[c];
                acc[c][0] = fmaf(a4.x, w, acc[c][0]);
                acc[c][1] = fmaf(a4.y, w, acc[c][1]);
                acc[c][2] = fmaf(a4.z, w, acc[c][2]);
                acc[c][3] = fmaf(a4.w, w, acc[c][3]);
            }
        }
    }

    const int n_c = blockIdx.x * NT + tpx * 4;
    const int b_c = n_c / ihiw;
    const int r_c = n_c % ihiw;
    const int i_c = r_c / IW;
    const int j_c = r_c % IW;
    const int oh = 2 * i_c + pr;
    float* __restrict__ ob = out + (size_t)b_c * CTOT * OH * OW + (size_t)oh * OW;
#pragma unroll
    for (int c = 0; c < CPTHD; c++) {
        const size_t off = (size_t)(co0 + c) * OH * OW;
#pragma unroll
        for (int q = 0; q < 4; q++)
            ob[off + 2 * (j_c + q) + pc] = fmaxf(acc[c][q], 0.0f);
    }
}

// Final transposed conv (32 -> 1). (validated)
__global__ __launch_bounds__(256) void convt2_quad(
    const float* __restrict__ in, const float* __restrict__ w,
    const float* __restrict__ bias, float* __restrict__ out, int B)
{
    const int IH = 128, IW = 128, CIN = 32, OW = 256;
    const int j = threadIdx.x & 127;
    const int i = (blockIdx.x << 1) + (threadIdx.x >> 7);
    const int b = blockIdx.y;

    const float* __restrict__ inb = in + (size_t)b * CIN * IH * IW;
    const float bz = bias[0];
    float a00 = bz, a01 = bz, a10 = bz, a11 = bz;

    const bool okm = (i > 0);
    const bool okp = (i < IH - 1);
    const bool olm = (j > 0);
    const bool olp = (j < IW - 1);

#pragma unroll 4
    for (int ci = 0; ci < CIN; ci++) {
        const float* __restrict__ p = inb + ((size_t)ci * IH + i) * IW + j;
        const float* __restrict__ wp = w + ci * 16;
        const float vmm = (okm && olm) ? p[-IW - 1] : 0.f;
        const float vm0 = okm ? p[-IW] : 0.f;
        const float vmp = (okm && olp) ? p[-IW + 1] : 0.f;
        const float v0m = olm ? p[-1] : 0.f;
        const float v00 = p[0];
        const float v0p = olp ? p[1] : 0.f;
        const float vpm = (okp && olm) ? p[IW - 1] : 0.f;
        const float vp0 = okp ? p[IW] : 0.f;
        const float vpp = (okp && olp) ? p[IW + 1] : 0.f;
        a00 = fmaf(v00, wp[1 * 4 + 1], a00);
        a00 = fmaf(v0m, wp[1 * 4 + 3], a00);
        a00 = fmaf(vm0, wp[3 * 4 + 1], a00);
        a00 = fmaf(vmm, wp[3 * 4 + 3], a00);
        a01 = fmaf(v0p, wp[1 * 4 + 0], a01);
        a01 = fmaf(v00, wp[1 * 4 + 2], a01);
        a01 = fmaf(vmp, wp[3 * 4 + 0], a01);
        a01 = fmaf(vm0, wp[3 * 4 + 2], a01);
        a10 = fmaf(vp0, wp[0 * 4 + 1], a10);
        a10 = fmaf(vpm, wp[0 * 4 + 3], a10);
        a10 = fmaf(v00, wp[2 * 4 + 1], a10);
        a10 = fmaf(v0m, wp[2 * 4 + 3], a10);
        a11 = fmaf(vpp, wp[0 * 4 + 0], a11);
        a11 = fmaf(vp0, wp[0 * 4 + 2], a11);
        a11 = fmaf(v0p, wp[2 * 4 + 0], a11);
        a11 = fmaf(v00, wp[2 * 4 + 2], a11);
    }

    float* __restrict__ outb = out + (size_t)b * 256 * 256;
    ((float2*)(outb + (size_t)(2 * i) * OW))[j] = make_float2(a00, a01);
    ((float2*)(outb + (size_t)(2 * i + 1) * OW))[j] = make_float2(a10, a11);
}

// VQ-GEMM. Block = 128 points (LDS-staged), 4 waves split 512 codes
// (128/wave); lane owns 2 points, codes scanned ascending in 8-chunks with
// strict <; cross-wave merge ascending w. All d values bit-identical to the
// sequential reference chains — DO NOT reorder any fmaf chain (R3).
__global__ __launch_bounds__(256) void vq_gemm(
    const float* __restrict__ h,    // (32,64,4096)
    const float* __restrict__ cb,   // (512,64) row-major (gather)
    const float* __restrict__ cbT,  // (64,512) dim-major (matmul)
    const float* __restrict__ ee,   // (512)
    float* __restrict__ q)          // (32,64,4096)
{
    __shared__ __align__(16) float As[64 * 128];
    __shared__ float xx_sh[128];
    __shared__ float pd[4 * 128];
    __shared__ int   pk[4 * 128];
    __shared__ int   bidx_sh[128];

    const int tid = threadIdx.x;
    const int tpx = tid & 63;
    const int w = __builtin_amdgcn_readfirstlane(tid >> 6);
    const int n0 = blockIdx.x * 128;
    const int b  = n0 >> 12;
    const int hw0 = n0 & 4095;

    // stage X-tile: As[dim][pt], coalesced reads
    const float* __restrict__ hb = h + (size_t)b * 64 * 4096 + hw0;
#pragma unroll
    for (int m = 0; m < 32; m++) {
        const int idx = m * 256 + tid;
        const int k = idx >> 7, p = idx & 127;
        As[idx] = hb[(size_t)k * 4096 + p];
    }
    __syncthreads();

    // xx per point (exact ascending chain over dims)
    if (tid < 128) {
        float s = 0.0f;
#pragma unroll
        for (int i = 0; i < 64; i++) {
            const float v = As[i * 128 + tid];
            s = fmaf(v, v, s);
        }
        xx_sh[tid] = s;
    }
    __syncthreads();

    const float xx0 = xx_sh[tpx * 2];
    const float xx1 = xx_sh[tpx * 2 + 1];
    const int cwave = w * 128;

    float best0 = 3.402823466e+38f, best1 = 3.402823466e+38f;
    int bk0 = 0, bk1 = 0;

#pragma unroll 1
    for (int ch = 0; ch < 16; ch++) {
        const int cbase = cwave + ch * 8;
        float acc[8][2];
#pragma unroll
        for (int c = 0; c < 8; c++) { acc[c][0] = 0.0f; acc[c][1] = 0.0f; }

#pragma unroll 8
        for (int k = 0; k < 64; k++) {
            const float2 a2 = *(const float2*)(As + k * 128 + tpx * 2);
            const float* __restrict__ wk = cbT + (size_t)k * 512 + cbase;
#pragma unroll
            for (int c = 0; c < 8; c++) {
                const float wv = wk[c];
                acc[c][0] = fmaf(a2.x, wv, acc[c][0]);
                acc[c][1] = fmaf(a2.y, wv, acc[c][1]);
            }
        }
        const float* __restrict__ eep = ee + cbase;
#pragma unroll
        for (int c = 0; c < 8; c++) {
            const float eec = eep[c];
            const float d0 = xx0 - 2.0f * acc[c][0] + eec;
            const float d1 = xx1 - 2.0f * acc[c][1] + eec;
            if (d0 < best0) { best0 = d0; bk0 = cbase + c; }
            if (d1 < best1) { best1 = d1; bk1 = cbase + c; }
        }
    }

    pd[w * 128 + tpx * 2]     = best0;
    pd[w * 128 + tpx * 2 + 1] = best1;
    pk[w * 128 + tpx * 2]     = bk0;
    pk[w * 128 + tpx * 2 + 1] = bk1;
    __syncthreads();

    // merge 4 wave-candidates per point (ascending w, strict <)
    if (tid < 128) {
        float bd = pd[tid]; int bk = pk[tid];
#pragma unroll
        for (int ww = 1; ww < 4; ww++) {
            const float od = pd[ww * 128 + tid];
            if (od < bd) { bd = od; bk = pk[ww * 128 + tid]; }
        }
        bidx_sh[tid] = bk;
    }
    __syncthreads();

    // gather + store: thread = (point = tid&127, dim-half = tid>>7)
    {
        const int p  = tid & 127;
        const int d0 = (tid >> 7) * 32;
        const int bk = bidx_sh[p];
        const float4* __restrict__ cp4 = (const float4*)(cb + (size_t)bk * 64 + d0);
        float* __restrict__ qb = q + ((size_t)b * 64 + d0) * 4096 + hw0 + p;
#pragma unroll
        for (int i = 0; i < 8; i++) {
            const float4 v = cp4[i];
            qb[(size_t)(4 * i + 0) * 4096] = v.x;
            qb[(size_t)(4 * i + 1) * 4096] = v.y;
            qb[(size_t)(4 * i + 2) * 4096] = v.z;
            qb[(size_t)(4 * i + 3) * 4096] = v.w;
        }
    }
}

extern "C" void kernel_launch(void* const* d_in, const int* in_sizes, int n_in,
                              void* d_out, int out_size, void* d_ws, size_t ws_size,
                              hipStream_t stream) {
    const float* x      = (const float*)d_in[0];
    const float* w_e1   = (const float*)d_in[1];
    const float* b_e1   = (const float*)d_in[2];
    const float* w_e2   = (const float*)d_in[3];
    const float* b_e2   = (const float*)d_in[4];
    const float* w_er1a = (const float*)d_in[5];
    const float* w_er1b = (const float*)d_in[6];
    const float* w_er2a = (const float*)d_in[7];
    const float* w_er2b = (const float*)d_in[8];
    const float* w_pre  = (const float*)d_in[9];
    const float* b_pre  = (const float*)d_in[10];
    const float* cbk    = (const float*)d_in[11];
    const float* w_d1   = (const float*)d_in[12];
    const float* b_d1   = (const float*)d_in[13];
    const float* w_dr1a = (const float*)d_in[14];
    const float* w_dr1b = (const float*)d_in[15];
    const float* w_dr2a = (const float*)d_in[16];
    const float* w_dr2b = (const float*)d_in[17];
    const float* w_t1   = (const float*)d_in[18];
    const float* b_t1   = (const float*)d_in[19];
    const float* w_t2   = (const float*)d_in[20];
    const float* b_t2   = (const float*)d_in[21];
    float* out = (float*)d_out;

    float* A  = (float*)d_ws;            // (32,32,128,128) = 16777216
    float* Bb = A  + 16777216;           // (32,64,64,64)   = 8388608
    float* C  = Bb + 8388608;            // (32,32,64,64)   = 4194304
    float* D  = C  + 4194304;            // (32,64,64,64)   = 8388608
    float* WR = D  + 8388608;            // repacked weights + cbT (221696)
    float* EE = WR + 221696;             // ee (512)

    float* r_e1  = WR;
    float* r_e2  = WR + 512;
    float* r_er1a = WR + 33280;
    float* r_er1b = WR + 51712;
    float* r_er2a = WR + 53760;
    float* r_er2b = WR + 72192;
    float* r_pre = WR + 74240;
    float* r_d1  = WR + 78336;
    float* r_dr1a = WR + 115200;
    float* r_dr1b = WR + 133632;
    float* r_dr2a = WR + 135680;
    float* r_dr2b = WR + 154112;
    float* r_t1  = WR + 156160;
    float* r_cbT = WR + 188928;

    const dim3 blk(256);

    repack_all<<<dim3(866), blk, 0, stream>>>(
        w_e1, w_e2, w_er1a, w_er1b, w_er2a, w_er2b, w_pre, w_d1,
        w_dr1a, w_dr1b, w_dr2a, w_dr2b, w_t1, cbk, WR);
    vq_prep_ee<<<dim3(2), blk, 0, stream>>>(cbk, EE);

    // Encoder
    conv_gemm<32, 32, 1, 4, 2, 1, false, true, false, true>
        <<<dim3(2048, 1), blk, 0, stream>>>(x, r_e1, b_e1, nullptr, A,
                                            256, 256, 128, 128);
    conv_gemm<64, 32, 32, 4, 2, 1, false, true, false, false>
        <<<dim3(512, 2), blk, 0, stream>>>(A, r_e2, b_e2, nullptr, Bb,
                                           128, 128, 64, 64);
    conv_gemm<32, 32, 64, 3, 1, 1, true, false, false, false>
        <<<dim3(512, 1), blk, 0, stream>>>(Bb, r_er1a, nullptr, nullptr, C,
                                           64, 64, 64, 64);
    conv_gemm<64, 32, 32, 1, 1, 0, true, false, true, false>
        <<<dim3(512, 2), blk, 0, stream>>>(C, r_er1b, nullptr, Bb, Bb,
                                           64, 64, 64, 64);
    conv_gemm<32, 32, 64, 3, 1, 1, true, false, false, false>
        <<<dim3(512, 1), blk, 0, stream>>>(Bb, r_er2a, nullptr, nullptr, C,
                                           64, 64, 64, 64);
    conv_gemm<64, 32, 32, 1, 1, 0, true, false, true, false>
        <<<dim3(512, 2), blk, 0, stream>>>(C, r_er2b, nullptr, Bb, Bb,
                                           64, 64, 64, 64);
    conv_gemm<64, 32, 64, 1, 1, 0, false, true, false, false>
        <<<dim3(512, 2), blk, 0, stream>>>(Bb, r_pre, b_pre, nullptr, D,
                                           64, 64, 64, 64);
    // VQ (GEMM form, 1024 blocks of 128 points)
    vq_gemm<<<dim3(1024), blk, 0, stream>>>(D, cbk, r_cbT, EE, Bb);
    // Decoder
    conv_gemm<64, 32, 64, 3, 1, 1, false, true, false, false>
        <<<dim3(512, 2), blk, 0, stream>>>(Bb, r_d1, b_d1, nullptr, D,
                                           64, 64, 64, 64);
    conv_gemm<32, 32, 64, 3, 1, 1, true, false, false, false>
        <<<dim3(512, 1), blk, 0, stream>>>(D, r_dr1a, nullptr, nullptr, C,
                                           64, 64, 64, 64);
    conv_gemm<64, 32, 32, 1, 1, 0, true, false, true, false>
        <<<dim3(512, 2), blk, 0, stream>>>(C, r_dr1b, nullptr, D, D,
                                           64, 64, 64, 64);
    conv_gemm<32, 32, 64, 3, 1, 1, true, false, false, false>
        <<<dim3(512, 1), blk, 0, stream>>>(D, r_dr2a, nullptr, nullptr, C,
                                           64, 64, 64, 64);
    conv_gemm<64, 32, 32, 1, 1, 0, true, false, true, false>
        <<<dim3(512, 2), blk, 0, stream>>>(C, r_dr2b, nullptr, D, D,
                                           64, 64, 64, 64);
    // t1
    convt_gemm<<<dim3(512, 4), blk, 0, stream>>>(D, r_t1, b_t1, A, 64, 64);
    // t2
    convt2_quad<<<dim3(64, 32), blk, 0, stream>>>(A, w_t2, b_t2, out, 32);
}